// Round 18
// baseline (113.627 us; speedup 1.0000x reference)
//
#include <hip/hip_runtime.h>

namespace {

constexpr int Cn   = 256;
constexpr int Hh   = 128;
constexpr int Ww   = 128;
constexpr int HW   = Hh * Ww;
constexpr int TILE = 16;
constexpr int CCH  = 8;              // channels per LDS chunk
constexpr int NCH  = Cn / CCH;       // 32 chunks
constexpr int HALO = 4;
constexpr int X2T  = 24;
constexpr int X2S  = 24;             // linear (gload_lds dest); 2-way read alias = free
constexpr int X2CH = X2T * X2S;      // 576 floats per channel
constexpr int NOFF = 81;

// 576 threads = 9 waves; wave wv <-> window row di = wv (o = 9*wv + dj).
// r18 geometry: lane l -> h = l&15 (tile row), m2 = (l>>4)&1 (px cols
// 8m2..8m2+7), c2 = l>>5 (2-way channel split, shfl-reduced at epilogue).
// Per lane per channel: ONE 16-float window (4 aligned b128) feeds 72 FMAs
// = 0.89 B/FMA (vs 1.78 at 4px/lane). x1 comes from GLOBAL (9 waves read
// identical addresses -> L1 broadcast; no LDS-pipe cost).
// Rationale: r12/r16/r17 (3 staging schemes) all ~97us profiled -> staging
// never the path; LDS bytes/FLOP is the invariant wall. This halves it.

__device__ __forceinline__ void gl2lds16(const float* g, float* l) {
  __builtin_amdgcn_global_load_lds(
      (const __attribute__((address_space(1))) void*)g,
      (__attribute__((address_space(3))) void*)l, 16, 0, 0);
}

__global__ __launch_bounds__(576, 1)
void costvol_kernel(const float* __restrict__ x1,
                    const float* __restrict__ x2,
                    const float* __restrict__ zp,   // >=16B zeros (d_ws)
                    float* __restrict__ out)
{
  __shared__ float sx2[2][CCH * X2CH];   // 2 x 18,432 B

  const int t  = threadIdx.x;
  const int wv = t >> 6;               // di = 0..8
  const int l  = t & 63;
  const int h  = l & 15;               // tile row 0..15
  const int m2 = (l >> 4) & 1;         // px half: cols 8m2..8m2+7
  const int c2 = l >> 5;               // channel half 0..1

  const int tx = blockIdx.x, ty = blockIdx.y, b = blockIdx.z;
  const int x0 = tx * TILE, y0 = ty * TILE;

  const float* g2 = x2 + (size_t)b * Cn * HW;
  // x1 lane base: row y0+h, cols x0+8m2.., channel base 4*c2 (+ k*8 + cc later)
  const float* g1 = x1 + (size_t)b * Cn * HW + (size_t)(4 * c2) * HW
                       + (size_t)(y0 + h) * Ww + (x0 + 8 * m2);

  // ---- x2 staging map (r17): slot s = t + 576*j; ch=s/144, row=(s%144)/6,
  //      col4=s%6; dest float4 idx = s (linear). OOB granule -> zp, inc 0. ----
  const float* gp0;  size_t inc0;
  const float* gp1;  size_t inc1;
  {
    const int s = t, ch = s / 144, rem = s % 144, row = rem / 6, c4 = rem % 6;
    const int gy = y0 - HALO + row, gx = x0 - HALO + 4 * c4;
    const bool ok = ((unsigned)gy < (unsigned)Hh) && (gx >= 0) && (gx + 3 < Ww);
    gp0  = ok ? (g2 + (size_t)ch * HW + (size_t)gy * Ww + gx) : zp;
    inc0 = ok ? (size_t)(CCH * HW) : 0;
  }
  {
    const int s = t + 576, ch = s / 144, rem = s % 144, row = rem / 6, c4 = rem % 6;
    const int gy = y0 - HALO + row, gx = x0 - HALO + 4 * c4;
    const bool ok = ((unsigned)gy < (unsigned)Hh) && (gx >= 0) && (gx + 3 < Ww);
    gp1  = ok ? (g2 + (size_t)ch * HW + (size_t)gy * Ww + gx) : zp;
    inc1 = ok ? (size_t)(CCH * HW) : 0;
  }
  const int lds0 = (t >> 6) * 256;          // wave-uniform float offsets
  const int lds1 = lds0 + 9 * 256;

  auto stage = [&](int nb) {
    gl2lds16(gp0, &sx2[nb][lds0]);  gp0 += inc0;
    gl2lds16(gp1, &sx2[nb][lds1]);  gp1 += inc1;
  };

  float acc[9][8];
#pragma unroll
  for (int d = 0; d < 9; ++d)
#pragma unroll
    for (int p = 0; p < 8; ++p) acc[d][p] = 0.0f;

  // lane's window: stage row (h+wv), stage cols 8m2..8m2+15 (w[i]=col 8m2+i;
  // out px p needs col 8m2+p+dj -> w[p+dj], p+dj<=15). 16B-aligned b128 x4.
  const int rbase = (h + wv) * X2S + 8 * m2;

  // ---- one channel: a (8 px, 2 global float4) + w (16 floats) -> 72 FMA ----
  auto chan = [&](int k, int cc, const float* sc) {
    const float* ga = g1 + (size_t)(k * CCH + cc) * HW;
    const float4 a0 = *reinterpret_cast<const float4*>(ga);
    const float4 a1 = *reinterpret_cast<const float4*>(ga + 4);
    const float* bp = sc + (4 * c2 + cc) * X2CH + rbase;
    float w[16];
    *reinterpret_cast<float4*>(w)      = *reinterpret_cast<const float4*>(bp);
    *reinterpret_cast<float4*>(w + 4)  = *reinterpret_cast<const float4*>(bp + 4);
    *reinterpret_cast<float4*>(w + 8)  = *reinterpret_cast<const float4*>(bp + 8);
    *reinterpret_cast<float4*>(w + 12) = *reinterpret_cast<const float4*>(bp + 12);
#pragma unroll
    for (int dj = 0; dj < 9; ++dj) {
      acc[dj][0] = fmaf(a0.x, w[dj + 0], acc[dj][0]);
      acc[dj][1] = fmaf(a0.y, w[dj + 1], acc[dj][1]);
      acc[dj][2] = fmaf(a0.z, w[dj + 2], acc[dj][2]);
      acc[dj][3] = fmaf(a0.w, w[dj + 3], acc[dj][3]);
      acc[dj][4] = fmaf(a1.x, w[dj + 4], acc[dj][4]);
      acc[dj][5] = fmaf(a1.y, w[dj + 5], acc[dj][5]);
      acc[dj][6] = fmaf(a1.z, w[dj + 6], acc[dj][6]);
      acc[dj][7] = fmaf(a1.w, w[dj + 7], acc[dj][7]);
    }
  };

  // ---- prologue: stage chunk 0 ----
  stage(0);
  asm volatile("s_waitcnt vmcnt(0)" ::: "memory");
  __syncthreads();

  for (int k = 0; k < NCH; ++k) {
    if (k + 1 < NCH) stage((k + 1) & 1);     // burst next chunk at phase top
    const float* sc = sx2[k & 1];
    chan(k, 0, sc);                          // lane's 4 channels (c2 half)
    chan(k, 1, sc);
    chan(k, 2, sc);
    chan(k, 3, sc);
    asm volatile("s_waitcnt vmcnt(0)" ::: "memory");
    __syncthreads();
  }

  // ---- epilogue: c2-reduce (lane l <-> l+32), then store; o = 9*wv + dj ----
#pragma unroll
  for (int dj = 0; dj < 9; ++dj)
#pragma unroll
    for (int p = 0; p < 8; ++p) {
      float v = acc[dj][p];
      v += __shfl_down(v, 32);
      acc[dj][p] = v;
    }

  if (l < 32) {                              // h = l&15, m2 = l>>4
    const float invc = 1.0f / (float)Cn;
    const int y  = y0 + h;
    const int xb = x0 + 8 * m2;
#pragma unroll
    for (int dj = 0; dj < 9; ++dj) {
      const int o = wv * 9 + dj;
      float* op = out + (((size_t)b * NOFF + o) * Hh + y) * Ww + xb;
      float4 v0, v1;
      v0.x = acc[dj][0] * invc; v0.y = acc[dj][1] * invc;
      v0.z = acc[dj][2] * invc; v0.w = acc[dj][3] * invc;
      v1.x = acc[dj][4] * invc; v1.y = acc[dj][5] * invc;
      v1.z = acc[dj][6] * invc; v1.w = acc[dj][7] * invc;
      *reinterpret_cast<float4*>(op)     = v0;
      *reinterpret_cast<float4*>(op + 4) = v1;
    }
  }
}

} // namespace

extern "C" void kernel_launch(void* const* d_in, const int* in_sizes, int n_in,
                              void* d_out, int out_size, void* d_ws, size_t ws_size,
                              hipStream_t stream) {
  const float* x1 = (const float*)d_in[0];
  const float* x2 = (const float*)d_in[1];
  float* out = (float*)d_out;

  hipMemsetAsync(d_ws, 0, 256, stream);   // 16B zero block for OOB halo

  dim3 grid(Ww / TILE, Hh / TILE, 4);   // 8 x 8 x 4 = 256 blocks (1/CU)
  dim3 block(576);                      // 9 waves: wave wv <-> window row di
  costvol_kernel<<<grid, block, 0, stream>>>(x1, x2, (const float*)d_ws, out);
}

// Round 19
// 107.777 us; speedup vs baseline: 1.0543x; 1.0543x over previous
//
#include <hip/hip_runtime.h>

namespace {

constexpr int Cn   = 256;
constexpr int Hh   = 128;
constexpr int Ww   = 128;
constexpr int HW   = Hh * Ww;
constexpr int TILE = 16;
constexpr int CCH  = 8;              // channels per LDS chunk
constexpr int NCH  = Cn / CCH;       // 32 chunks
constexpr int HALO = 4;
constexpr int X2T  = 24;
constexpr int X2S  = 24;             // linear (gload_lds dest); 2-way read alias = free
constexpr int X2CH = X2T * X2S;      // 576 floats per channel
constexpr int X1CH = TILE * TILE;    // 256 floats per channel
constexpr int NOFF = 81;

// 576 threads = 9 waves; wave wv <-> window row di = wv (o = 9*wv + dj).
// Lane l: h = l>>2 (tile row), m = l&3 (cols 4m..4m+3).  [r17 compute, verbatim]
// r19 = r17 + T3/T4: triple-buffered gload_lds staging with COUNTED vmcnt.
// Every wave issues exactly 3 gload_lds per stage (wave 8 stages zp->dump so
// counts are wave-uniform); loop waits vmcnt(3) -- chunk k+1 landed, k+2
// stays in flight (~54KB/CU outstanding) -- then raw s_barrier (NOT
// __syncthreads, which emits vmcnt(0) and drains the pipeline).
// Evidence: r12/r16/r17 all ~97-101us with drain-to-0 phases; the residual
// ~3.8K cyc/phase is the drain stall, the only uncovered catalog lever.

__device__ __forceinline__ void gl2lds16(const float* g, float* l) {
  __builtin_amdgcn_global_load_lds(
      (const __attribute__((address_space(1))) void*)g,
      (__attribute__((address_space(3))) void*)l, 16, 0, 0);
}

__global__ __launch_bounds__(576, 1)
void costvol_kernel(const float* __restrict__ x1,
                    const float* __restrict__ x2,
                    const float* __restrict__ zp,   // >=16B of zeros (d_ws)
                    float* __restrict__ out)
{
  __shared__ float sx2[3][CCH * X2CH];   // 3 x 18,432 B
  __shared__ float sx1[3][CCH * X1CH];   // 3 x  8,192 B
  __shared__ float dump[64 * 4];         // wave-8 dummy x1 slot (1 KB)

  const int t    = threadIdx.x;
  const int wv   = t >> 6;             // di = 0..8
  const int lane = t & 63;
  const int h    = lane >> 2;          // tile row 0..15
  const int m    = lane & 3;           // pixel group: cols 4m..4m+3

  const int tx = blockIdx.x, ty = blockIdx.y, b = blockIdx.z;
  const int x0 = tx * TILE, y0 = ty * TILE;

  const float* g2 = x2 + (size_t)b * Cn * HW;

  // ---- x2 staging: slot s = t + 576*j -> ch=s/144, row=(s%144)/6, col4=s%6;
  //      dest float4 idx = s (linear). OOB halo granule -> zp, inc 0. ----
  const float* gp0;  size_t inc0;
  const float* gp1;  size_t inc1;
  {
    const int s = t, ch = s / 144, rem = s % 144, row = rem / 6, c4 = rem % 6;
    const int gy = y0 - HALO + row, gx = x0 - HALO + 4 * c4;
    const bool ok = ((unsigned)gy < (unsigned)Hh) && (gx >= 0) && (gx + 3 < Ww);
    gp0  = ok ? (g2 + (size_t)ch * HW + (size_t)gy * Ww + gx) : zp;
    inc0 = ok ? (size_t)(CCH * HW) : 0;
  }
  {
    const int s = t + 576, ch = s / 144, rem = s % 144, row = rem / 6, c4 = rem % 6;
    const int gy = y0 - HALO + row, gx = x0 - HALO + 4 * c4;
    const bool ok = ((unsigned)gy < (unsigned)Hh) && (gx >= 0) && (gx + 3 < Ww);
    gp1  = ok ? (g2 + (size_t)ch * HW + (size_t)gy * Ww + gx) : zp;
    inc1 = ok ? (size_t)(CCH * HW) : 0;
  }
  const int lds0 = (t >> 6) * 256;          // wave-uniform float offsets
  const int lds1 = lds0 + 9 * 256;

  // ---- x1 staging: wave w<8 stages channel (k*CCH+w)'s 16x16 tile;
  //      lane l -> [ch=w][row=h][col=4m] (always in range). Wave 8 -> dump. --
  const float* gpx;  size_t incx;  float* x1base;  int x1str;
  if (wv < 8) {
    gpx    = x1 + (size_t)b * Cn * HW + (size_t)wv * HW
                + (size_t)(y0 + h) * Ww + (x0 + 4 * m);
    incx   = (size_t)(CCH * HW);
    x1base = &sx1[0][wv * X1CH];
    x1str  = CCH * X1CH;                 // floats between buffers
  } else {
    gpx    = zp;
    incx   = 0;
    x1base = dump;
    x1str  = 0;
  }

  float* const sx2f = &sx2[0][0];
  float* const sx1f = &sx1[0][0];

  auto stage = [&](int nb) {             // exactly 3 gload_lds per thread
    gl2lds16(gp0, sx2f + nb * (CCH * X2CH) + lds0);  gp0 += inc0;
    gl2lds16(gp1, sx2f + nb * (CCH * X2CH) + lds1);  gp1 += inc1;
    gl2lds16(gpx, x1base + nb * x1str);              gpx += incx;
  };

  float acc[9][4];
#pragma unroll
  for (int d = 0; d < 9; ++d)
#pragma unroll
    for (int p = 0; p < 4; ++p) acc[d][p] = 0.0f;

  const int rbase = (h + wv) * X2S + 4 * m;
  const int abase = h * TILE + 4 * m;       // x1 LDS read: granule l exactly

  // ---- batched 4-channel group: pure-LDS operands, then 144 FMAs ----
  auto quad = [&](int hc, const float* sc, const float* s1c) {
    float4 a[4];
    float  w[4][12];
#pragma unroll
    for (int cc = 0; cc < 4; ++cc) {
      a[cc] = *reinterpret_cast<const float4*>(s1c + (4 * hc + cc) * X1CH + abase);
      const float* bp = sc + (4 * hc + cc) * X2CH + rbase;
      *reinterpret_cast<float4*>(w[cc])     = *reinterpret_cast<const float4*>(bp);
      *reinterpret_cast<float4*>(w[cc] + 4) = *reinterpret_cast<const float4*>(bp + 4);
      *reinterpret_cast<float4*>(w[cc] + 8) = *reinterpret_cast<const float4*>(bp + 8);
    }
#pragma unroll
    for (int cc = 0; cc < 4; ++cc)
#pragma unroll
      for (int dj = 0; dj < 9; ++dj) {
        acc[dj][0] = fmaf(a[cc].x, w[cc][dj + 0], acc[dj][0]);
        acc[dj][1] = fmaf(a[cc].y, w[cc][dj + 1], acc[dj][1]);
        acc[dj][2] = fmaf(a[cc].z, w[cc][dj + 2], acc[dj][2]);
        acc[dj][3] = fmaf(a[cc].w, w[cc][dj + 3], acc[dj][3]);
      }
  };

  // ---- prologue: chunks 0,1 in flight; wait chunk 0 only ----
  stage(0);
  stage(1);
  asm volatile("s_waitcnt vmcnt(3)" ::: "memory");   // chunk 0 landed
  __builtin_amdgcn_s_barrier();
  __builtin_amdgcn_sched_barrier(0);

  for (int k = 0; k < NCH; ++k) {
    if (k + 2 < NCH) stage((k + 2) % 3);   // keep 2 chunks (~54KB/CU) in flight
    const float* sc  = sx2f + (k % 3) * (CCH * X2CH);
    const float* s1c = sx1f + (k % 3) * (CCH * X1CH);
    quad(0, sc, s1c);
    quad(1, sc, s1c);
    if (k + 2 < NCH) {
      asm volatile("s_waitcnt vmcnt(3)" ::: "memory");  // k+1 landed; k+2 in flight
    } else {
      asm volatile("s_waitcnt vmcnt(0)" ::: "memory");  // tail drain
    }
    __builtin_amdgcn_s_barrier();          // raw: no implicit vmcnt(0)
    __builtin_amdgcn_sched_barrier(0);
  }

  // ---- epilogue: o = 9*di + dj; each (b,o,y,x) written exactly once ----
  const float invc = 1.0f / (float)Cn;
  const int y  = y0 + h;
  const int xb = x0 + 4 * m;
#pragma unroll
  for (int dj = 0; dj < 9; ++dj) {
    const int o = wv * 9 + dj;
    float4 v;
    v.x = acc[dj][0] * invc;
    v.y = acc[dj][1] * invc;
    v.z = acc[dj][2] * invc;
    v.w = acc[dj][3] * invc;
    *reinterpret_cast<float4*>(out + (((size_t)b * NOFF + o) * Hh + y) * Ww + xb) = v;
  }
}

} // namespace

extern "C" void kernel_launch(void* const* d_in, const int* in_sizes, int n_in,
                              void* d_out, int out_size, void* d_ws, size_t ws_size,
                              hipStream_t stream) {
  const float* x1 = (const float*)d_in[0];
  const float* x2 = (const float*)d_in[1];
  float* out = (float*)d_out;

  hipMemsetAsync(d_ws, 0, 256, stream);   // 16B zero block for OOB halo

  dim3 grid(Ww / TILE, Hh / TILE, 4);   // 8 x 8 x 4 = 256 blocks (1/CU)
  dim3 block(576);                      // 9 waves: wave wv <-> window row di
  costvol_kernel<<<grid, block, 0, stream>>>(x1, x2, (const float*)d_ws, out);
}